// Round 21
// baseline (259.900 us; speedup 1.0000x reference)
//
#include <hip/hip_runtime.h>
#include <math.h>

#define S 128
#define R 384
#define CM 256
#define CZ 128
#define H 8
#define D 32
#define INFB 1e9f
#define LN_EPS 1e-5f
#define LOG2E 1.4426950408889634f

typedef unsigned short u16;
typedef short bf16x8 __attribute__((ext_vector_type(8)));
typedef short bf16x4 __attribute__((ext_vector_type(4)));
typedef float f32x4 __attribute__((ext_vector_type(4)));

#define NRTOT ((size_t)S * R)   // 49152 rows

__device__ inline float wave_reduce_sum(float v) {
    #pragma unroll
    for (int o = 32; o > 0; o >>= 1) v += __shfl_xor(v, o, 64);
    return v;
}

__device__ inline u16 f2bf(float f) {
    union { float f; unsigned int u; } x; x.f = f;
    unsigned int r = x.u + 0x7fffu + ((x.u >> 16) & 1u);
    return (u16)(r >> 16);
}

__device__ inline float bf2f(u16 v) {
    union { unsigned int u; float f; } x; x.u = ((unsigned int)v) << 16;
    return x.f;
}

// ---------------------------------------------------------------------------
// mask -> mlog[s][key] = (mask-1)*INF*LOG2E  (hoists per-iter VALU prep)
__global__ __launch_bounds__(256) void maskprep_kernel(
    const float* __restrict__ mask, float* __restrict__ mlog) {
    int i = blockIdx.x * 256 + threadIdx.x;   // 192 blocks cover 49152
    float4 mk = ((const float4*)mask)[i];
    const float MSC = INFB * LOG2E;
    float4 r;
    r.x = (mk.x - 1.0f) * MSC;
    r.y = (mk.y - 1.0f) * MSC;
    r.z = (mk.z - 1.0f) * MSC;
    r.w = (mk.w - 1.0f) * MSC;
    ((float4*)mlog)[i] = r;
}

// ---------------------------------------------------------------------------
// Weight prep -> TILED Wt[mi][n/16][kk][n%16][32] (dense 1KB GEMM B-frags).
// mi: 0=q(scaled),1=k,2=v,3=g,4=o
__global__ __launch_bounds__(256) void wprep_kernel(
    const float* __restrict__ wq, const float* __restrict__ wk,
    const float* __restrict__ wv, const float* __restrict__ wg,
    const float* __restrict__ wo, u16* __restrict__ Wt) {
    int n = blockIdx.x & 255;
    int mi = blockIdx.x >> 8;
    int kc = threadIdx.x;
    const float* src = mi == 0 ? wq : mi == 1 ? wk : mi == 2 ? wv
                     : mi == 3 ? wg : wo;
    float val = src[(size_t)kc * 256 + n];
    if (mi == 0) val *= 0.17677669529663687f * LOG2E;
    size_t dst = (size_t)mi * 65536 + (size_t)(n >> 4) * 4096
               + (size_t)(kc >> 5) * 512 + (n & 15) * 32 + (kc & 31);
    Wt[dst] = f2bf(val);
}

// ---------------------------------------------------------------------------
// LN(m) -> TILED At[row/16][kk][row%16][32] bf16. 4 rows per block.
__global__ __launch_bounds__(256) void lnm_kernel(
    const float* __restrict__ m, const float* __restrict__ lnw,
    const float* __restrict__ lnb, u16* __restrict__ A) {
    int t = threadIdx.x;
    int wave = t >> 6, lane = t & 63;
    size_t row = (size_t)blockIdx.x * 4 + wave;
    float4 x = ((const float4*)(m + row * 256))[lane];
    float ss = wave_reduce_sum(x.x + x.y + x.z + x.w);
    float sq = wave_reduce_sum(x.x * x.x + x.y * x.y + x.z * x.z + x.w * x.w);
    float mu = ss * (1.0f / 256.0f);
    float var = sq * (1.0f / 256.0f) - mu * mu;
    float rstd = rsqrtf(var + LN_EPS);
    int c = lane * 4;
    ushort4 o4;
    o4.x = f2bf((x.x - mu) * rstd * lnw[c]     + lnb[c]);
    o4.y = f2bf((x.y - mu) * rstd * lnw[c + 1] + lnb[c + 1]);
    o4.z = f2bf((x.z - mu) * rstd * lnw[c + 2] + lnb[c + 2]);
    o4.w = f2bf((x.w - mu) * rstd * lnw[c + 3] + lnb[c + 3]);
    size_t dst = (row >> 4) * 4096 + (size_t)(lane >> 3) * 512
               + (row & 15) * 32 + (lane & 7) * 4;
    *(ushort4*)(A + dst) = o4;
}

// ---------------------------------------------------------------------------
// z_bias: TILED zbT[h][j/16][i][j%16]; pre-scaled by LOG2E.
__global__ __launch_bounds__(256) void zbias_kernel(
    const float* __restrict__ z, const float* __restrict__ lnw,
    const float* __restrict__ lnb, const float* __restrict__ wz,
    float* __restrict__ zbias) {
    int t = threadIdx.x;
    int lane = t & 63, wave = t >> 6;
    int g = lane >> 4, u = lane & 15;
    int c0 = u * 8;

    float lw[8], lb[8];
    {
        float4 a = *(const float4*)(lnw + c0);
        float4 b = *(const float4*)(lnw + c0 + 4);
        lw[0]=a.x; lw[1]=a.y; lw[2]=a.z; lw[3]=a.w;
        lw[4]=b.x; lw[5]=b.y; lw[6]=b.z; lw[7]=b.w;
        float4 c = *(const float4*)(lnb + c0);
        float4 d = *(const float4*)(lnb + c0 + 4);
        lb[0]=c.x; lb[1]=c.y; lb[2]=c.z; lb[3]=c.w;
        lb[4]=d.x; lb[5]=d.y; lb[6]=d.z; lb[7]=d.w;
        #pragma unroll
        for (int i = 0; i < 8; ++i) { lw[i] *= LOG2E; lb[i] *= LOG2E; }
    }
    float uw[8][8];
    float bwp[8];
    #pragma unroll
    for (int h = 0; h < 8; ++h) bwp[h] = 0.f;
    #pragma unroll
    for (int i = 0; i < 8; ++i) {
        float4 w0 = *(const float4*)(wz + (size_t)(c0 + i) * 8);
        float4 w1 = *(const float4*)(wz + (size_t)(c0 + i) * 8 + 4);
        uw[i][0] = lw[i] * w0.x; uw[i][1] = lw[i] * w0.y;
        uw[i][2] = lw[i] * w0.z; uw[i][3] = lw[i] * w0.w;
        uw[i][4] = lw[i] * w1.x; uw[i][5] = lw[i] * w1.y;
        uw[i][6] = lw[i] * w1.z; uw[i][7] = lw[i] * w1.w;
        bwp[0] = fmaf(lb[i], w0.x, bwp[0]); bwp[1] = fmaf(lb[i], w0.y, bwp[1]);
        bwp[2] = fmaf(lb[i], w0.z, bwp[2]); bwp[3] = fmaf(lb[i], w0.w, bwp[3]);
        bwp[4] = fmaf(lb[i], w1.x, bwp[4]); bwp[5] = fmaf(lb[i], w1.y, bwp[5]);
        bwp[6] = fmaf(lb[i], w1.z, bwp[6]); bwp[7] = fmaf(lb[i], w1.w, bwp[7]);
    }

    const int nwaves = gridDim.x * 4;
    int wid = blockIdx.x * 4 + wave;
    #pragma unroll 1
    for (int it = 0; it < 4; ++it) {
        int p = (wid + it * nwaves) * 4 + g;
        const float* zp = z + (size_t)p * CZ + c0;
        float4 z0 = *(const float4*)zp;
        float4 z1 = *(const float4*)(zp + 4);
        float x[8] = {z0.x, z0.y, z0.z, z0.w, z1.x, z1.y, z1.z, z1.w};
        float ss = 0.f, sq = 0.f;
        #pragma unroll
        for (int i = 0; i < 8; ++i) { ss += x[i]; sq = fmaf(x[i], x[i], sq); }
        #pragma unroll
        for (int o = 1; o < 16; o <<= 1) {
            ss += __shfl_xor(ss, o, 64);
            sq += __shfl_xor(sq, o, 64);
        }
        float mu = ss * (1.0f / CZ);
        float var = sq * (1.0f / CZ) - mu * mu;
        float rstd = rsqrtf(var + LN_EPS);
        float ph[8];
        #pragma unroll
        for (int h = 0; h < 8; ++h) ph[h] = bwp[h];
        #pragma unroll
        for (int i = 0; i < 8; ++i) {
            float ti = (x[i] - mu) * rstd;
            #pragma unroll
            for (int h = 0; h < 8; ++h) ph[h] = fmaf(ti, uw[i][h], ph[h]);
        }
        #pragma unroll
        for (int h = 0; h < 8; ++h) {
            #pragma unroll
            for (int o = 1; o < 16; o <<= 1) ph[h] += __shfl_xor(ph[h], o, 64);
        }
        if (u < 8) {
            float outv = ph[0];
            if (u == 1) outv = ph[1];
            if (u == 2) outv = ph[2];
            if (u == 3) outv = ph[3];
            if (u == 4) outv = ph[4];
            if (u == 5) outv = ph[5];
            if (u == 6) outv = ph[6];
            if (u == 7) outv = ph[7];
            int i = p / R;           // q row
            int j = p - i * R;       // key
            zbias[(((size_t)u * 24 + (j >> 4)) * R + i) * 16 + (j & 15)] = outv;
        }
    }
}

// ---------------------------------------------------------------------------
// qkvg GEMM: TILED At / Wt reads (dense 1KB frags). HEAD-MAJOR q,k,g;
// v -> TILED slot-permuted vTt[s][h][key32][dt][d%16][slot32].
__global__ __launch_bounds__(512) void qkvg_gemm(
    const u16* __restrict__ A, const u16* __restrict__ Wt,
    const float* __restrict__ bg,
    u16* __restrict__ q, u16* __restrict__ k, u16* __restrict__ vT,
    u16* __restrict__ g) {
    int nb = blockIdx.y;
    size_t row0 = (size_t)blockIdx.x * 128;
    int t = threadIdx.x, lane = t & 63, wave = t >> 6;
    int l15 = lane & 15, l4 = lane >> 4;
    int wm = (wave >> 2) * 64, wn = (wave & 3) * 64;
    const u16* B = Wt + (size_t)nb * 65536;
    size_t arb = (row0 + wm) >> 4;   // A row-block base
    int nblk = wn >> 4;
    int lelem = l15 * 32 + l4 * 8;

    f32x4 acc[4][4];
    #pragma unroll
    for (int mt = 0; mt < 4; ++mt)
        #pragma unroll
        for (int nt = 0; nt < 4; ++nt)
            acc[mt][nt] = (f32x4){0.f, 0.f, 0.f, 0.f};

    #pragma unroll
    for (int kk = 0; kk < 8; ++kk) {
        bf16x8 af[4], bfr[4];
        #pragma unroll
        for (int mt = 0; mt < 4; ++mt)
            af[mt] = *(const bf16x8*)(A + ((arb + mt) * 8 + kk) * 512 + lelem);
        #pragma unroll
        for (int nt = 0; nt < 4; ++nt)
            bfr[nt] = *(const bf16x8*)(B + ((size_t)(nblk + nt) * 8 + kk) * 512 + lelem);
        #pragma unroll
        for (int mt = 0; mt < 4; ++mt)
            #pragma unroll
            for (int nt = 0; nt < 4; ++nt)
                acc[mt][nt] = __builtin_amdgcn_mfma_f32_16x16x32_bf16(
                    af[mt], bfr[nt], acc[mt][nt], 0, 0, 0);
    }

    if (nb == 3) {
        #pragma unroll
        for (int nt = 0; nt < 4; ++nt) {
            int col = wn + nt * 16 + l15;
            int hh = col >> 5, dd = col & 31;
            float bgv = bg[col];
            #pragma unroll
            for (int mt = 0; mt < 4; ++mt)
                #pragma unroll
                for (int r = 0; r < 4; ++r) {
                    size_t row = row0 + wm + mt * 16 + l4 * 4 + r;
                    g[((size_t)hh * NRTOT + row) * 32 + dd] =
                        f2bf(1.0f / (1.0f + __expf(-(acc[mt][nt][r] + bgv))));
                }
        }
    } else if (nb == 2) {
        #pragma unroll
        for (int nt = 0; nt < 4; ++nt) {
            int col = wn + nt * 16 + l15;
            int hh = col >> 5, dd = col & 31;
            int dt = dd >> 4, d15 = dd & 15;
            #pragma unroll
            for (int mt = 0; mt < 4; ++mt) {
                size_t row = row0 + wm + mt * 16 + l4 * 4;  // 4-aligned
                int ss = (int)(row / 384);
                int rr = (int)(row - (size_t)ss * 384);
                int kb = rr >> 5;
                int k5 = rr & 31;
                int slot = ((k5 & 15) >> 2) * 8 + ((k5 & 16) ? 4 : 0);
                ushort4 pk;
                pk.x = f2bf(acc[mt][nt][0]);
                pk.y = f2bf(acc[mt][nt][1]);
                pk.z = f2bf(acc[mt][nt][2]);
                pk.w = f2bf(acc[mt][nt][3]);
                size_t off = ((((size_t)(ss * 8 + hh) * 12 + kb) * 2 + dt) * 16
                              + d15) * 32 + slot;
                *(ushort4*)(vT + off) = pk;
            }
        }
    } else {
        u16* dst = nb == 0 ? q : k;
        #pragma unroll
        for (int nt = 0; nt < 4; ++nt) {
            int col = wn + nt * 16 + l15;
            int hh = col >> 5, dd = col & 31;
            #pragma unroll
            for (int mt = 0; mt < 4; ++mt)
                #pragma unroll
                for (int r = 0; r < 4; ++r) {
                    size_t row = row0 + wm + mt * 16 + l4 * 4 + r;
                    dst[((size_t)hh * NRTOT + row) * 32 + dd] = f2bf(acc[mt][nt][r]);
                }
        }
    }
}

// ---------------------------------------------------------------------------
// out GEMM: A = o HEAD-MAJOR [h][S*R][32] (dense); B = TILED Wt[4].
__global__ __launch_bounds__(512) void out_gemm(
    const u16* __restrict__ A, const u16* __restrict__ Wt,
    const float* __restrict__ bo, float* __restrict__ out) {
    size_t row0 = (size_t)blockIdx.x * 128;
    int t = threadIdx.x, lane = t & 63, wave = t >> 6;
    int l15 = lane & 15, l4 = lane >> 4;
    int wm = (wave >> 2) * 64, wn = (wave & 3) * 64;
    int nblk = wn >> 4;
    int lelem = l15 * 32 + l4 * 8;

    f32x4 acc[4][4];
    #pragma unroll
    for (int mt = 0; mt < 4; ++mt)
        #pragma unroll
        for (int nt = 0; nt < 4; ++nt)
            acc[mt][nt] = (f32x4){0.f, 0.f, 0.f, 0.f};

    #pragma unroll
    for (int kk = 0; kk < 8; ++kk) {
        bf16x8 af[4], bfr[4];
        #pragma unroll
        for (int mt = 0; mt < 4; ++mt)
            af[mt] = *(const bf16x8*)(A +
                ((size_t)kk * NRTOT + row0 + wm + mt * 16 + l15) * 32 + l4 * 8);
        #pragma unroll
        for (int nt = 0; nt < 4; ++nt)
            bfr[nt] = *(const bf16x8*)(Wt + ((size_t)(nblk + nt) * 8 + kk) * 512 + lelem);
        #pragma unroll
        for (int mt = 0; mt < 4; ++mt)
            #pragma unroll
            for (int nt = 0; nt < 4; ++nt)
                acc[mt][nt] = __builtin_amdgcn_mfma_f32_16x16x32_bf16(
                    af[mt], bfr[nt], acc[mt][nt], 0, 0, 0);
    }

    #pragma unroll
    for (int nt = 0; nt < 4; ++nt) {
        int col = wn + nt * 16 + l15;
        float bov = bo[col];
        #pragma unroll
        for (int mt = 0; mt < 4; ++mt)
            #pragma unroll
            for (int r = 0; r < 4; ++r) {
                size_t row = row0 + wm + mt * 16 + l4 * 4 + r;
                out[row * 256 + col] = acc[mt][nt][r] + bov;
            }
    }
}

// ---------------------------------------------------------------------------
// Attention v15: v13 structure (768 thr, 12 waves — best measured) with
// VALU diet round 2: precomputed mlog (no per-iter mask prep) and 1-op
// truncation bf16 pack (consistent across numerator and denominator).
__global__ __launch_bounds__(768) void attn_kernel(
    const u16* __restrict__ q, const u16* __restrict__ k,
    const u16* __restrict__ vT, const u16* __restrict__ g,
    const float* __restrict__ mlog, const float* __restrict__ zb,
    u16* __restrict__ o) {
    int h = blockIdx.x, s = blockIdx.y;
    int t = threadIdx.x;
    int lane = t & 63, wave = t >> 6;   // wave in [0,12)
    int l15 = lane & 15, l4 = lane >> 4;

    size_t hbase = ((size_t)h * NRTOT + (size_t)s * R) * 32;
    const u16* qh = q + hbase;
    const u16* kh = k + hbase;
    const u16* gh = g + hbase;
    u16* oh = o + hbase;
    const u16* vbase = vT + (size_t)(s * H + h) * 12 * 1024;
    const float* zbh = zb + (size_t)h * 24 * R * 16;
    const float* mrow = mlog + (size_t)s * R;

    int wq0 = wave * 32;
    bf16x8 qf[2];
    #pragma unroll
    for (int rt = 0; rt < 2; ++rt)
        qf[rt] = *(const bf16x8*)(qh + (size_t)(wq0 + rt * 16 + l15) * 32 + l4 * 8);

    bf16x8 ones;
    #pragma unroll
    for (int i = 0; i < 8; ++i) ones[i] = (short)0x3F80;  // bf16 1.0

    f32x4 oacc[2][2];
    f32x4 pdacc[2];
    #pragma unroll
    for (int rt = 0; rt < 2; ++rt) {
        pdacc[rt] = (f32x4){0.f, 0.f, 0.f, 0.f};
        #pragma unroll
        for (int dt = 0; dt < 2; ++dt)
            oacc[rt][dt] = (f32x4){0.f, 0.f, 0.f, 0.f};
    }

    for (int kt = 0; kt < R; kt += 32) {
        int kb = kt >> 5;
        bf16x8 kf0 = *(const bf16x8*)(kh + (size_t)(kt + l15) * 32 + l4 * 8);
        bf16x8 kf1 = *(const bf16x8*)(kh + (size_t)(kt + 16 + l15) * 32 + l4 * 8);
        bf16x8 vb0 = *(const bf16x8*)(vbase + ((size_t)kb * 2 + 0) * 512
                                      + l15 * 32 + l4 * 8);
        bf16x8 vb1 = *(const bf16x8*)(vbase + ((size_t)kb * 2 + 1) * 512
                                      + l15 * 32 + l4 * 8);
        float4 ml0 = *(const float4*)(mrow + kt + l4 * 4);
        float4 ml1 = *(const float4*)(mrow + kt + 16 + l4 * 4);
        f32x4 zv0[2], zv1[2];
        #pragma unroll
        for (int rt = 0; rt < 2; ++rt) {
            zv0[rt] = *(const f32x4*)(zbh +
                ((size_t)(2 * kb) * R + wq0 + rt * 16 + l15) * 16 + l4 * 4);
            zv1[rt] = *(const f32x4*)(zbh +
                ((size_t)(2 * kb + 1) * R + wq0 + rt * 16 + l15) * 16 + l4 * 4);
        }

        const f32x4 z4 = {0.f, 0.f, 0.f, 0.f};
        f32x4 sf0[2], sf1[2];
        #pragma unroll
        for (int rt = 0; rt < 2; ++rt) {
            sf0[rt] = __builtin_amdgcn_mfma_f32_16x16x32_bf16(kf0, qf[rt], z4, 0, 0, 0);
            sf1[rt] = __builtin_amdgcn_mfma_f32_16x16x32_bf16(kf1, qf[rt], z4, 0, 0, 0);
        }

        #pragma unroll
        for (int rt = 0; rt < 2; ++rt) {
            float e0 = exp2f(sf0[rt][0] + ml0.x + zv0[rt][0]);
            float e1 = exp2f(sf0[rt][1] + ml0.y + zv0[rt][1]);
            float e2 = exp2f(sf0[rt][2] + ml0.z + zv0[rt][2]);
            float e3 = exp2f(sf0[rt][3] + ml0.w + zv0[rt][3]);
            float e4 = exp2f(sf1[rt][0] + ml1.x + zv1[rt][0]);
            float e5 = exp2f(sf1[rt][1] + ml1.y + zv1[rt][1]);
            float e6 = exp2f(sf1[rt][2] + ml1.z + zv1[rt][2]);
            float e7 = exp2f(sf1[rt][3] + ml1.w + zv1[rt][3]);
            bf16x8 pa;
            pa[0] = (short)(__float_as_uint(e0) >> 16);
            pa[1] = (short)(__float_as_uint(e1) >> 16);
            pa[2] = (short)(__float_as_uint(e2) >> 16);
            pa[3] = (short)(__float_as_uint(e3) >> 16);
            pa[4] = (short)(__float_as_uint(e4) >> 16);
            pa[5] = (short)(__float_as_uint(e5) >> 16);
            pa[6] = (short)(__float_as_uint(e6) >> 16);
            pa[7] = (short)(__float_as_uint(e7) >> 16);
            oacc[rt][0] = __builtin_amdgcn_mfma_f32_16x16x32_bf16(
                pa, vb0, oacc[rt][0], 0, 0, 0);
            oacc[rt][1] = __builtin_amdgcn_mfma_f32_16x16x32_bf16(
                pa, vb1, oacc[rt][1], 0, 0, 0);
            pdacc[rt] = __builtin_amdgcn_mfma_f32_16x16x32_bf16(
                pa, ones, pdacc[rt], 0, 0, 0);
        }
    }

    // epilogue: pdacc[rt][r] is the denominator for qrow rt*16 + l4*4 + r
    #pragma unroll
    for (int rt = 0; rt < 2; ++rt) {
        #pragma unroll
        for (int r = 0; r < 4; ++r) {
            float inv = 1.0f / pdacc[rt][r];
            int qrow = wq0 + rt * 16 + l4 * 4 + r;
            #pragma unroll
            for (int dt = 0; dt < 2; ++dt) {
                size_t off = (size_t)qrow * 32 + dt * 16 + l15;
                oh[off] = f2bf(oacc[rt][dt][r] * inv * bf2f(gh[off]));
            }
        }
    }
}

extern "C" void kernel_launch(void* const* d_in, const int* in_sizes, int n_in,
                              void* d_out, int out_size, void* d_ws, size_t ws_size,
                              hipStream_t stream) {
    (void)in_sizes; (void)n_in; (void)out_size; (void)ws_size;
    const float* m      = (const float*)d_in[0];
    const float* z      = (const float*)d_in[1];
    const float* mask   = (const float*)d_in[2];
    const float* ln_m_w = (const float*)d_in[3];
    const float* ln_m_b = (const float*)d_in[4];
    const float* ln_z_w = (const float*)d_in[5];
    const float* ln_z_b = (const float*)d_in[6];
    const float* w_z    = (const float*)d_in[7];
    const float* w_q    = (const float*)d_in[8];
    const float* w_k    = (const float*)d_in[9];
    const float* w_v    = (const float*)d_in[10];
    const float* w_g    = (const float*)d_in[11];
    const float* b_g    = (const float*)d_in[12];
    const float* w_o    = (const float*)d_in[13];
    const float* b_o    = (const float*)d_in[14];
    float* out = (float*)d_out;
    char* wsb = (char*)d_ws;

    const size_t NR = NRTOT;  // 49152 rows
    u16*   A    = (u16*)wsb;                     wsb += NR * 256 * 2;
    u16*   q    = (u16*)wsb;                     wsb += NR * 256 * 2;
    u16*   k    = (u16*)wsb;                     wsb += NR * 256 * 2;
    u16*   vT   = (u16*)wsb;                     wsb += NR * 256 * 2;
    u16*   o    = (u16*)wsb;                     wsb += NR * 256 * 2;
    u16*   g    = (u16*)wsb;                     wsb += NR * 256 * 2;
    float* zbp  = (float*)wsb;                   wsb += (size_t)H * R * R * 4;
    u16*   Wt   = (u16*)wsb;                     wsb += (size_t)5 * 256 * 256 * 2;
    float* mlog = (float*)wsb;                   wsb += NR * 4;

    maskprep_kernel<<<48, 256, 0, stream>>>(mask, mlog);
    wprep_kernel<<<5 * 256, 256, 0, stream>>>(w_q, w_k, w_v, w_g, w_o, Wt);
    lnm_kernel<<<NR / 4, 256, 0, stream>>>(m, ln_m_w, ln_m_b, A);
    zbias_kernel<<<2304, 256, 0, stream>>>(z, ln_z_w, ln_z_b, w_z, zbp);
    qkvg_gemm<<<dim3(NR / 128, 4), 512, 0, stream>>>(A, Wt, b_g, q, k, vT, g);
    attn_kernel<<<dim3(H, S), 768, 0, stream>>>(q, k, vT, g, mlog, zbp, o);
    out_gemm<<<NR / 128, 512, 0, stream>>>(o, Wt + (size_t)4 * 65536, b_o, out);
}

// Round 22
// 248.647 us; speedup vs baseline: 1.0453x; 1.0453x over previous
//
#include <hip/hip_runtime.h>
#include <math.h>

#define S 128
#define R 384
#define CM 256
#define CZ 128
#define H 8
#define D 32
#define INFB 1e9f
#define LN_EPS 1e-5f
#define LOG2E 1.4426950408889634f

typedef unsigned short u16;
typedef short bf16x8 __attribute__((ext_vector_type(8)));
typedef float f32x4 __attribute__((ext_vector_type(4)));

#define NRTOT ((size_t)S * R)   // 49152 rows

__device__ inline float wave_reduce_sum(float v) {
    #pragma unroll
    for (int o = 32; o > 0; o >>= 1) v += __shfl_xor(v, o, 64);
    return v;
}

__device__ inline u16 f2bf(float f) {
    union { float f; unsigned int u; } x; x.f = f;
    unsigned int r = x.u + 0x7fffu + ((x.u >> 16) & 1u);
    return (u16)(r >> 16);
}

__device__ inline float bf2f(u16 v) {
    union { unsigned int u; float f; } x; x.u = ((unsigned int)v) << 16;
    return x.f;
}

// ---------------------------------------------------------------------------
// FUSED prep: lnm (blocks [0,12288)) + wprep ([12288,13568)) + maskprep
// ([13568,13616)). All independent; 256 threads.
__global__ __launch_bounds__(256) void prep_kernel(
    const float* __restrict__ m, const float* __restrict__ lnw,
    const float* __restrict__ lnb, u16* __restrict__ A,
    const float* __restrict__ wq, const float* __restrict__ wk,
    const float* __restrict__ wv, const float* __restrict__ wg,
    const float* __restrict__ wo, u16* __restrict__ Wt,
    const float* __restrict__ mask, float* __restrict__ mlog) {
    int bid = blockIdx.x;
    int t = threadIdx.x;
    if (bid < 12288) {
        // --- LN(m) -> TILED At[row/16][kk][row%16][32]
        int wave = t >> 6, lane = t & 63;
        size_t row = (size_t)bid * 4 + wave;
        float4 x = ((const float4*)(m + row * 256))[lane];
        float ss = wave_reduce_sum(x.x + x.y + x.z + x.w);
        float sq = wave_reduce_sum(x.x * x.x + x.y * x.y + x.z * x.z + x.w * x.w);
        float mu = ss * (1.0f / 256.0f);
        float var = sq * (1.0f / 256.0f) - mu * mu;
        float rstd = rsqrtf(var + LN_EPS);
        int c = lane * 4;
        ushort4 o4;
        o4.x = f2bf((x.x - mu) * rstd * lnw[c]     + lnb[c]);
        o4.y = f2bf((x.y - mu) * rstd * lnw[c + 1] + lnb[c + 1]);
        o4.z = f2bf((x.z - mu) * rstd * lnw[c + 2] + lnb[c + 2]);
        o4.w = f2bf((x.w - mu) * rstd * lnw[c + 3] + lnb[c + 3]);
        size_t dst = (row >> 4) * 4096 + (size_t)(lane >> 3) * 512
                   + (row & 15) * 32 + (lane & 7) * 4;
        *(ushort4*)(A + dst) = o4;
    } else if (bid < 13568) {
        // --- weights -> TILED Wt[mi][n/16][kk][n%16][32]
        int b = bid - 12288;
        int n = b & 255;
        int mi = b >> 8;
        int kc = t;
        const float* src = mi == 0 ? wq : mi == 1 ? wk : mi == 2 ? wv
                         : mi == 3 ? wg : wo;
        float val = src[(size_t)kc * 256 + n];
        if (mi == 0) val *= 0.17677669529663687f * LOG2E;
        size_t dst = (size_t)mi * 65536 + (size_t)(n >> 4) * 4096
                   + (size_t)(kc >> 5) * 512 + (n & 15) * 32 + (kc & 31);
        Wt[dst] = f2bf(val);
    } else {
        // --- mask -> mlog = (mask-1)*INF*LOG2E (float4 per thread)
        int i = (bid - 13568) * 256 + t;   // 48 blocks cover 12288 float4s
        float4 mk = ((const float4*)mask)[i];
        const float MSC = INFB * LOG2E;
        float4 r;
        r.x = (mk.x - 1.0f) * MSC;
        r.y = (mk.y - 1.0f) * MSC;
        r.z = (mk.z - 1.0f) * MSC;
        r.w = (mk.w - 1.0f) * MSC;
        ((float4*)mlog)[i] = r;
    }
}

// ---------------------------------------------------------------------------
// FUSED main: grid (384, 7), 512 threads.
//   blockIdx.y < 4 : qkvg GEMM (nb = blockIdx.y) — TILED At/Wt reads,
//                    HEAD-MAJOR q,k,g; v -> TILED slot-permuted vTt.
//   blockIdx.y >= 4: zbias — TILED zbT[h][j/16][i][j%16], LOG2E-prescaled.
// Independent inputs/outputs; complementary pipes overlap on the CUs.
__global__ __launch_bounds__(512) void main_fused(
    const u16* __restrict__ A, const u16* __restrict__ Wt,
    const float* __restrict__ bg,
    u16* __restrict__ q, u16* __restrict__ k, u16* __restrict__ vT,
    u16* __restrict__ g,
    const float* __restrict__ z, const float* __restrict__ lnw,
    const float* __restrict__ lnb, const float* __restrict__ wz,
    float* __restrict__ zbias) {
    int t = threadIdx.x, lane = t & 63, wave = t >> 6;
    int l15 = lane & 15, l4 = lane >> 4;

    if (blockIdx.y < 4) {
        // ================= qkvg GEMM =================
        int nb = blockIdx.y;
        size_t row0 = (size_t)blockIdx.x * 128;
        int wm = (wave >> 2) * 64, wn = (wave & 3) * 64;
        const u16* B = Wt + (size_t)nb * 65536;
        size_t arb = (row0 + wm) >> 4;
        int nblk = wn >> 4;
        int lelem = l15 * 32 + l4 * 8;

        f32x4 acc[4][4];
        #pragma unroll
        for (int mt = 0; mt < 4; ++mt)
            #pragma unroll
            for (int nt = 0; nt < 4; ++nt)
                acc[mt][nt] = (f32x4){0.f, 0.f, 0.f, 0.f};

        #pragma unroll
        for (int kk = 0; kk < 8; ++kk) {
            bf16x8 af[4], bfr[4];
            #pragma unroll
            for (int mt = 0; mt < 4; ++mt)
                af[mt] = *(const bf16x8*)(A + ((arb + mt) * 8 + kk) * 512 + lelem);
            #pragma unroll
            for (int nt = 0; nt < 4; ++nt)
                bfr[nt] = *(const bf16x8*)(B + ((size_t)(nblk + nt) * 8 + kk) * 512 + lelem);
            #pragma unroll
            for (int mt = 0; mt < 4; ++mt)
                #pragma unroll
                for (int nt = 0; nt < 4; ++nt)
                    acc[mt][nt] = __builtin_amdgcn_mfma_f32_16x16x32_bf16(
                        af[mt], bfr[nt], acc[mt][nt], 0, 0, 0);
        }

        if (nb == 3) {
            #pragma unroll
            for (int nt = 0; nt < 4; ++nt) {
                int col = wn + nt * 16 + l15;
                int hh = col >> 5, dd = col & 31;
                float bgv = bg[col];
                #pragma unroll
                for (int mt = 0; mt < 4; ++mt)
                    #pragma unroll
                    for (int r = 0; r < 4; ++r) {
                        size_t row = row0 + wm + mt * 16 + l4 * 4 + r;
                        g[((size_t)hh * NRTOT + row) * 32 + dd] =
                            f2bf(1.0f / (1.0f + __expf(-(acc[mt][nt][r] + bgv))));
                    }
            }
        } else if (nb == 2) {
            #pragma unroll
            for (int nt = 0; nt < 4; ++nt) {
                int col = wn + nt * 16 + l15;
                int hh = col >> 5, dd = col & 31;
                int dt = dd >> 4, d15 = dd & 15;
                #pragma unroll
                for (int mt = 0; mt < 4; ++mt) {
                    size_t row = row0 + wm + mt * 16 + l4 * 4;
                    int ss = (int)(row / 384);
                    int rr = (int)(row - (size_t)ss * 384);
                    int kb = rr >> 5;
                    int k5 = rr & 31;
                    int slot = ((k5 & 15) >> 2) * 8 + ((k5 & 16) ? 4 : 0);
                    ushort4 pk;
                    pk.x = f2bf(acc[mt][nt][0]);
                    pk.y = f2bf(acc[mt][nt][1]);
                    pk.z = f2bf(acc[mt][nt][2]);
                    pk.w = f2bf(acc[mt][nt][3]);
                    size_t off = ((((size_t)(ss * 8 + hh) * 12 + kb) * 2 + dt) * 16
                                  + d15) * 32 + slot;
                    *(ushort4*)(vT + off) = pk;
                }
            }
        } else {
            u16* dst = nb == 0 ? q : k;
            #pragma unroll
            for (int nt = 0; nt < 4; ++nt) {
                int col = wn + nt * 16 + l15;
                int hh = col >> 5, dd = col & 31;
                #pragma unroll
                for (int mt = 0; mt < 4; ++mt)
                    #pragma unroll
                    for (int r = 0; r < 4; ++r) {
                        size_t row = row0 + wm + mt * 16 + l4 * 4 + r;
                        dst[((size_t)hh * NRTOT + row) * 32 + dd] = f2bf(acc[mt][nt][r]);
                    }
            }
        }
    } else {
        // ================= zbias =================
        int gidx = lane >> 4, u = lane & 15;
        int c0 = u * 8;

        float lw[8], lb[8];
        {
            float4 a = *(const float4*)(lnw + c0);
            float4 b = *(const float4*)(lnw + c0 + 4);
            lw[0]=a.x; lw[1]=a.y; lw[2]=a.z; lw[3]=a.w;
            lw[4]=b.x; lw[5]=b.y; lw[6]=b.z; lw[7]=b.w;
            float4 c = *(const float4*)(lnb + c0);
            float4 d = *(const float4*)(lnb + c0 + 4);
            lb[0]=c.x; lb[1]=c.y; lb[2]=c.z; lb[3]=c.w;
            lb[4]=d.x; lb[5]=d.y; lb[6]=d.z; lb[7]=d.w;
            #pragma unroll
            for (int i = 0; i < 8; ++i) { lw[i] *= LOG2E; lb[i] *= LOG2E; }
        }
        float uw[8][8];
        float bwp[8];
        #pragma unroll
        for (int h = 0; h < 8; ++h) bwp[h] = 0.f;
        #pragma unroll
        for (int i = 0; i < 8; ++i) {
            float4 w0 = *(const float4*)(wz + (size_t)(c0 + i) * 8);
            float4 w1 = *(const float4*)(wz + (size_t)(c0 + i) * 8 + 4);
            uw[i][0] = lw[i] * w0.x; uw[i][1] = lw[i] * w0.y;
            uw[i][2] = lw[i] * w0.z; uw[i][3] = lw[i] * w0.w;
            uw[i][4] = lw[i] * w1.x; uw[i][5] = lw[i] * w1.y;
            uw[i][6] = lw[i] * w1.z; uw[i][7] = lw[i] * w1.w;
            bwp[0] = fmaf(lb[i], w0.x, bwp[0]); bwp[1] = fmaf(lb[i], w0.y, bwp[1]);
            bwp[2] = fmaf(lb[i], w0.z, bwp[2]); bwp[3] = fmaf(lb[i], w0.w, bwp[3]);
            bwp[4] = fmaf(lb[i], w1.x, bwp[4]); bwp[5] = fmaf(lb[i], w1.y, bwp[5]);
            bwp[6] = fmaf(lb[i], w1.z, bwp[6]); bwp[7] = fmaf(lb[i], w1.w, bwp[7]);
        }

        // 1152 blocks * 8 waves = 9216 wave-slots; 4 pairs/wave/iter * 4 iters
        int zbid = (blockIdx.y - 4) * 384 + blockIdx.x;
        int wid = zbid * 8 + wave;
        const int nwaves = 9216;
        #pragma unroll 1
        for (int it = 0; it < 4; ++it) {
            int p = (wid + it * nwaves) * 4 + gidx;
            const float* zp = z + (size_t)p * CZ + c0;
            float4 z0 = *(const float4*)zp;
            float4 z1 = *(const float4*)(zp + 4);
            float x[8] = {z0.x, z0.y, z0.z, z0.w, z1.x, z1.y, z1.z, z1.w};
            float ss = 0.f, sq = 0.f;
            #pragma unroll
            for (int i = 0; i < 8; ++i) { ss += x[i]; sq = fmaf(x[i], x[i], sq); }
            #pragma unroll
            for (int o = 1; o < 16; o <<= 1) {
                ss += __shfl_xor(ss, o, 64);
                sq += __shfl_xor(sq, o, 64);
            }
            float mu = ss * (1.0f / CZ);
            float var = sq * (1.0f / CZ) - mu * mu;
            float rstd = rsqrtf(var + LN_EPS);
            float ph[8];
            #pragma unroll
            for (int h = 0; h < 8; ++h) ph[h] = bwp[h];
            #pragma unroll
            for (int i = 0; i < 8; ++i) {
                float ti = (x[i] - mu) * rstd;
                #pragma unroll
                for (int h = 0; h < 8; ++h) ph[h] = fmaf(ti, uw[i][h], ph[h]);
            }
            #pragma unroll
            for (int h = 0; h < 8; ++h) {
                #pragma unroll
                for (int o = 1; o < 16; o <<= 1) ph[h] += __shfl_xor(ph[h], o, 64);
            }
            if (u < 8) {
                float outv = ph[0];
                if (u == 1) outv = ph[1];
                if (u == 2) outv = ph[2];
                if (u == 3) outv = ph[3];
                if (u == 4) outv = ph[4];
                if (u == 5) outv = ph[5];
                if (u == 6) outv = ph[6];
                if (u == 7) outv = ph[7];
                int i = p / R;           // q row
                int j = p - i * R;       // key
                zbias[(((size_t)u * 24 + (j >> 4)) * R + i) * 16 + (j & 15)] = outv;
            }
        }
    }
}

// ---------------------------------------------------------------------------
// out GEMM: A = o HEAD-MAJOR [h][S*R][32] (dense); B = TILED Wt[4].
__global__ __launch_bounds__(512) void out_gemm(
    const u16* __restrict__ A, const u16* __restrict__ Wt,
    const float* __restrict__ bo, float* __restrict__ out) {
    size_t row0 = (size_t)blockIdx.x * 128;
    int t = threadIdx.x, lane = t & 63, wave = t >> 6;
    int l15 = lane & 15, l4 = lane >> 4;
    int wm = (wave >> 2) * 64, wn = (wave & 3) * 64;
    int nblk = wn >> 4;
    int lelem = l15 * 32 + l4 * 8;

    f32x4 acc[4][4];
    #pragma unroll
    for (int mt = 0; mt < 4; ++mt)
        #pragma unroll
        for (int nt = 0; nt < 4; ++nt)
            acc[mt][nt] = (f32x4){0.f, 0.f, 0.f, 0.f};

    #pragma unroll
    for (int kk = 0; kk < 8; ++kk) {
        bf16x8 af[4], bfr[4];
        #pragma unroll
        for (int mt = 0; mt < 4; ++mt)
            af[mt] = *(const bf16x8*)(A +
                ((size_t)kk * NRTOT + row0 + wm + mt * 16 + l15) * 32 + l4 * 8);
        #pragma unroll
        for (int nt = 0; nt < 4; ++nt)
            bfr[nt] = *(const bf16x8*)(Wt + ((size_t)(nblk + nt) * 8 + kk) * 512 + lelem);
        #pragma unroll
        for (int mt = 0; mt < 4; ++mt)
            #pragma unroll
            for (int nt = 0; nt < 4; ++nt)
                acc[mt][nt] = __builtin_amdgcn_mfma_f32_16x16x32_bf16(
                    af[mt], bfr[nt], acc[mt][nt], 0, 0, 0);
    }

    #pragma unroll
    for (int nt = 0; nt < 4; ++nt) {
        int col = wn + nt * 16 + l15;
        float bov = bo[col];
        #pragma unroll
        for (int mt = 0; mt < 4; ++mt)
            #pragma unroll
            for (int r = 0; r < 4; ++r) {
                size_t row = row0 + wm + mt * 16 + l4 * 4 + r;
                out[row * 256 + col] = acc[mt][nt][r] + bov;
            }
    }
}

// ---------------------------------------------------------------------------
// Attention v16 (= v13 structure, best measured): 768 thr / 12 waves,
// dense loads, MFMA-computed denominator, +0x8000 rounding pack, mlog.
__global__ __launch_bounds__(768) void attn_kernel(
    const u16* __restrict__ q, const u16* __restrict__ k,
    const u16* __restrict__ vT, const u16* __restrict__ g,
    const float* __restrict__ mlog, const float* __restrict__ zb,
    u16* __restrict__ o) {
    int h = blockIdx.x, s = blockIdx.y;
    int t = threadIdx.x;
    int lane = t & 63, wave = t >> 6;   // wave in [0,12)
    int l15 = lane & 15, l4 = lane >> 4;

    size_t hbase = ((size_t)h * NRTOT + (size_t)s * R) * 32;
    const u16* qh = q + hbase;
    const u16* kh = k + hbase;
    const u16* gh = g + hbase;
    u16* oh = o + hbase;
    const u16* vbase = vT + (size_t)(s * H + h) * 12 * 1024;
    const float* zbh = zb + (size_t)h * 24 * R * 16;
    const float* mrow = mlog + (size_t)s * R;

    int wq0 = wave * 32;
    bf16x8 qf[2];
    #pragma unroll
    for (int rt = 0; rt < 2; ++rt)
        qf[rt] = *(const bf16x8*)(qh + (size_t)(wq0 + rt * 16 + l15) * 32 + l4 * 8);

    bf16x8 ones;
    #pragma unroll
    for (int i = 0; i < 8; ++i) ones[i] = (short)0x3F80;  // bf16 1.0

    f32x4 oacc[2][2];
    f32x4 pdacc[2];
    #pragma unroll
    for (int rt = 0; rt < 2; ++rt) {
        pdacc[rt] = (f32x4){0.f, 0.f, 0.f, 0.f};
        #pragma unroll
        for (int dt = 0; dt < 2; ++dt)
            oacc[rt][dt] = (f32x4){0.f, 0.f, 0.f, 0.f};
    }

    for (int kt = 0; kt < R; kt += 32) {
        int kb = kt >> 5;
        bf16x8 kf0 = *(const bf16x8*)(kh + (size_t)(kt + l15) * 32 + l4 * 8);
        bf16x8 kf1 = *(const bf16x8*)(kh + (size_t)(kt + 16 + l15) * 32 + l4 * 8);
        bf16x8 vb0 = *(const bf16x8*)(vbase + ((size_t)kb * 2 + 0) * 512
                                      + l15 * 32 + l4 * 8);
        bf16x8 vb1 = *(const bf16x8*)(vbase + ((size_t)kb * 2 + 1) * 512
                                      + l15 * 32 + l4 * 8);
        float4 ml0 = *(const float4*)(mrow + kt + l4 * 4);
        float4 ml1 = *(const float4*)(mrow + kt + 16 + l4 * 4);
        f32x4 zv0[2], zv1[2];
        #pragma unroll
        for (int rt = 0; rt < 2; ++rt) {
            zv0[rt] = *(const f32x4*)(zbh +
                ((size_t)(2 * kb) * R + wq0 + rt * 16 + l15) * 16 + l4 * 4);
            zv1[rt] = *(const f32x4*)(zbh +
                ((size_t)(2 * kb + 1) * R + wq0 + rt * 16 + l15) * 16 + l4 * 4);
        }

        const f32x4 z4 = {0.f, 0.f, 0.f, 0.f};
        f32x4 sf0[2], sf1[2];
        #pragma unroll
        for (int rt = 0; rt < 2; ++rt) {
            sf0[rt] = __builtin_amdgcn_mfma_f32_16x16x32_bf16(kf0, qf[rt], z4, 0, 0, 0);
            sf1[rt] = __builtin_amdgcn_mfma_f32_16x16x32_bf16(kf1, qf[rt], z4, 0, 0, 0);
        }

        #pragma unroll
        for (int rt = 0; rt < 2; ++rt) {
            float e0 = exp2f(sf0[rt][0] + ml0.x + zv0[rt][0]);
            float e1 = exp2f(sf0[rt][1] + ml0.y + zv0[rt][1]);
            float e2 = exp2f(sf0[rt][2] + ml0.z + zv0[rt][2]);
            float e3 = exp2f(sf0[rt][3] + ml0.w + zv0[rt][3]);
            float e4 = exp2f(sf1[rt][0] + ml1.x + zv1[rt][0]);
            float e5 = exp2f(sf1[rt][1] + ml1.y + zv1[rt][1]);
            float e6 = exp2f(sf1[rt][2] + ml1.z + zv1[rt][2]);
            float e7 = exp2f(sf1[rt][3] + ml1.w + zv1[rt][3]);
            bf16x8 pa;
            pa[0] = (short)((__float_as_uint(e0) + 0x8000u) >> 16);
            pa[1] = (short)((__float_as_uint(e1) + 0x8000u) >> 16);
            pa[2] = (short)((__float_as_uint(e2) + 0x8000u) >> 16);
            pa[3] = (short)((__float_as_uint(e3) + 0x8000u) >> 16);
            pa[4] = (short)((__float_as_uint(e4) + 0x8000u) >> 16);
            pa[5] = (short)((__float_as_uint(e5) + 0x8000u) >> 16);
            pa[6] = (short)((__float_as_uint(e6) + 0x8000u) >> 16);
            pa[7] = (short)((__float_as_uint(e7) + 0x8000u) >> 16);
            oacc[rt][0] = __builtin_amdgcn_mfma_f32_16x16x32_bf16(
                pa, vb0, oacc[rt][0], 0, 0, 0);
            oacc[rt][1] = __builtin_amdgcn_mfma_f32_16x16x32_bf16(
                pa, vb1, oacc[rt][1], 0, 0, 0);
            pdacc[rt] = __builtin_amdgcn_mfma_f32_16x16x32_bf16(
                pa, ones, pdacc[rt], 0, 0, 0);
        }
    }

    #pragma unroll
    for (int rt = 0; rt < 2; ++rt) {
        #pragma unroll
        for (int r = 0; r < 4; ++r) {
            float inv = 1.0f / pdacc[rt][r];
            int qrow = wq0 + rt * 16 + l4 * 4 + r;
            #pragma unroll
            for (int dt = 0; dt < 2; ++dt) {
                size_t off = (size_t)qrow * 32 + dt * 16 + l15;
                oh[off] = f2bf(oacc[rt][dt][r] * inv * bf2f(gh[off]));
            }
        }
    }
}

extern "C" void kernel_launch(void* const* d_in, const int* in_sizes, int n_in,
                              void* d_out, int out_size, void* d_ws, size_t ws_size,
                              hipStream_t stream) {
    (void)in_sizes; (void)n_in; (void)out_size; (void)ws_size;
    const float* m      = (const float*)d_in[0];
    const float* z      = (const float*)d_in[1];
    const float* mask   = (const float*)d_in[2];
    const float* ln_m_w = (const float*)d_in[3];
    const float* ln_m_b = (const float*)d_in[4];
    const float* ln_z_w = (const float*)d_in[5];
    const float* ln_z_b = (const float*)d_in[6];
    const float* w_z    = (const float*)d_in[7];
    const float* w_q    = (const float*)d_in[8];
    const float* w_k    = (const float*)d_in[9];
    const float* w_v    = (const float*)d_in[10];
    const float* w_g    = (const float*)d_in[11];
    const float* b_g    = (const float*)d_in[12];
    const float* w_o    = (const float*)d_in[13];
    const float* b_o    = (const float*)d_in[14];
    float* out = (float*)d_out;
    char* wsb = (char*)d_ws;

    const size_t NR = NRTOT;  // 49152 rows
    u16*   A    = (u16*)wsb;                     wsb += NR * 256 * 2;
    u16*   q    = (u16*)wsb;                     wsb += NR * 256 * 2;
    u16*   k    = (u16*)wsb;                     wsb += NR * 256 * 2;
    u16*   vT   = (u16*)wsb;                     wsb += NR * 256 * 2;
    u16*   o    = (u16*)wsb;                     wsb += NR * 256 * 2;
    u16*   g    = (u16*)wsb;                     wsb += NR * 256 * 2;
    float* zbp  = (float*)wsb;                   wsb += (size_t)H * R * R * 4;
    u16*   Wt   = (u16*)wsb;                     wsb += (size_t)5 * 256 * 256 * 2;
    float* mlog = (float*)wsb;                   wsb += NR * 4;

    prep_kernel<<<13616, 256, 0, stream>>>(m, ln_m_w, ln_m_b, A,
                                           w_q, w_k, w_v, w_g, w_o, Wt,
                                           mask, mlog);
    main_fused<<<dim3(384, 7), 512, 0, stream>>>(A, Wt, b_g, q, k, vT, g,
                                                 z, ln_z_w, ln_z_b, w_z, zbp);
    attn_kernel<<<dim3(H, S), 768, 0, stream>>>(q, k, vT, g, mlog, zbp, o);
    out_gemm<<<NR / 128, 512, 0, stream>>>(o, Wt + (size_t)4 * 65536, b_o, out);
}